// Round 15
// baseline (129.651 us; speedup 1.0000x reference)
//
#include <hip/hip_runtime.h>

// ---------------------------------------------------------------------------
// MemoryCausalSelfAttention for MI355X (gfx950).
// Model (R4-R11): per-CU staging rate = ~3.4 B/cyc x resident blocks/CU.
// qkv GEMM: 64x128 tile, 24KB LDS -> 6 blocks/CU (grid 1536) for 2x rate.
// proj GEMM: split-K=2 (template) + f32 combine pass (validated ~24us R11).
// Fused prep/cvt; flash attention (XCD-local, balanced pairs, LDS K/V).
// Causal mask over concat axis => only first 1024 keys ever attended.
// ---------------------------------------------------------------------------

using u16    = unsigned short;
using bf16x8 = __attribute__((ext_vector_type(8))) __bf16;
using f32x4  = __attribute__((ext_vector_type(4))) float;
using u16x8  = __attribute__((ext_vector_type(8))) unsigned short;
using u16x4  = __attribute__((ext_vector_type(4))) unsigned short;

__device__ __forceinline__ u16 f2bf(float f) {
    union { float f; unsigned u; } v; v.f = f;
    unsigned r = v.u + 0x7FFFu + ((v.u >> 16) & 1u);   // RNE
    return (u16)(r >> 16);
}

__device__ __forceinline__ void gload16(const void* src, const void* lds_base) {
    __builtin_amdgcn_global_load_lds(
        (const __attribute__((address_space(1))) void*)src,
        (__attribute__((address_space(3))) void*)lds_base, 16, 0, 0);
}

// ------------------- fused f32->bf16 conversions (x, Wqkv, Wproj) ----------
__global__ __launch_bounds__(256) void cvt_all(const float* __restrict__ x,
                                               const float* __restrict__ wa,
                                               const float* __restrict__ wp,
                                               u16* __restrict__ xb,
                                               u16* __restrict__ wab,
                                               u16* __restrict__ wpb) {
    int i = blockIdx.x * 256 + threadIdx.x;      // 2,097,152 float4 units total
    const float4* s; u16x4* d; int j;
    if (i < 1048576)      { s = (const float4*)x;  d = (u16x4*)xb;  j = i; }
    else if (i < 1835008) { s = (const float4*)wa; d = (u16x4*)wab; j = i - 1048576; }
    else                  { s = (const float4*)wp; d = (u16x4*)wpb; j = i - 1835008; }
    float4 f = s[j];
    u16x4 o; o[0] = f2bf(f.x); o[1] = f2bf(f.y); o[2] = f2bf(f.z); o[3] = f2bf(f.w);
    d[j] = o;
}

// ---- fused mem prep: copy k1/v1/k2/v2 + conv(k=2,s=2,p=1)+LN for k3/v3 ----
__global__ __launch_bounds__(256) void prep_mem(const float* __restrict__ k1,
                                                const float* __restrict__ v1,
                                                const float* __restrict__ k2,
                                                const float* __restrict__ v2,
                                                const float* __restrict__ k3,
                                                const float* __restrict__ v3,
                                                const float* __restrict__ wk,
                                                const float* __restrict__ gk,
                                                const float* __restrict__ bk,
                                                const float* __restrict__ wv,
                                                const float* __restrict__ gv,
                                                const float* __restrict__ bv,
                                                u16* __restrict__ all_k,
                                                u16* __restrict__ all_v) {
    const int bh = blockIdx.y;
    const int ru = blockIdx.x * 4 + (threadIdx.x >> 6);
    const int d = threadIdx.x & 63;
    if (ru >= 1286) return;
    if (ru < 772) {                                   // plain copies
        const float* src; u16* dst; int t, ro, L;
        if (ru < 129)      { t = ru;       src = k1; dst = all_k; ro = 0;   L = 129; }
        else if (ru < 258) { t = ru - 129; src = v1; dst = all_v; ro = 0;   L = 129; }
        else if (ru < 515) { t = ru - 258; src = k2; dst = all_k; ro = 129; L = 257; }
        else               { t = ru - 515; src = v2; dst = all_v; ro = 129; L = 257; }
        float v = src[((size_t)bh * L + t) * 64 + d];
        dst[((size_t)bh * 1024 + ro + t) * 64 + d] = f2bf(v);
    } else {                                          // compress + LN (ro=386)
        const float* seg; const float* w; const float* g; const float* bta; u16* dst; int t;
        if (ru < 1029) { t = ru - 772;  seg = k3; w = wk; g = gk; bta = bk; dst = all_k; }
        else           { t = ru - 1029; seg = v3; w = wv; g = gv; bta = bv; dst = all_v; }
        const float* sb = seg + (size_t)bh * 513 * 64;
        float x0 = (t > 0) ? sb[(size_t)(2 * t - 1) * 64 + d] : 0.f;
        float x1 = sb[(size_t)(2 * t) * 64 + d];
        float y = w[2 * d] * x0 + w[2 * d + 1] * x1;
        float s = y;
        #pragma unroll
        for (int o = 32; o; o >>= 1) s += __shfl_xor(s, o);
        float mu = s * (1.f / 64.f);
        float dv = y - mu;
        float s2 = dv * dv;
        #pragma unroll
        for (int o = 32; o; o >>= 1) s2 += __shfl_xor(s2, o);
        float var = s2 * (1.f / 64.f);
        float out = dv * rsqrtf(var + 1e-5f) * g[d] + bta[d];
        dst[((size_t)bh * 1024 + 386 + t) * 64 + d] = f2bf(out);
    }
}

// ----------------- V transpose: [bh][1024][64] -> [bh][64][1024] -----------
__global__ __launch_bounds__(256) void transpose_v(const u16* __restrict__ src,
                                                   u16* __restrict__ dst) {
    __shared__ u16 tile[64][66];
    const int bh = blockIdx.y, t0 = blockIdx.x * 64;
    const int tid = threadIdx.x;
    #pragma unroll
    for (int i = 0; i < 2; ++i) {
        int p = tid + i * 256;
        int tr = p >> 3, dc = (p & 7) * 8;
        *(u16x8*)&tile[tr][dc] = *(const u16x8*)&src[((size_t)bh * 1024 + t0 + tr) * 64 + dc];
    }
    __syncthreads();
    #pragma unroll
    for (int i = 0; i < 2; ++i) {
        int p = tid + i * 256;
        int d = p >> 3, tc = (p & 7) * 8;
        u16x8 v;
        #pragma unroll
        for (int e = 0; e < 8; ++e) v[e] = tile[tc + e][d];
        *(u16x8*)&dst[((size_t)bh * 64 + d) * 1024 + t0 + tc] = v;
    }
}

// --------- qkv GEMM: 64x128 tile, BK=32, 24KB dbuf LDS, 6 blocks/CU --------
// A [M][K]=x_bf, W [N][K]=wq. 4 waves side-by-side in n (each 64 rows x 32
// cols, acc[4][2]). Per iter: frag reads -> stage(t+1) (A 1 + B 2 gload16
// per thread) -> 8 MFMA -> barrier. Swizzle X(row)=((row>>1)&3)<<4 applied
// both-sides. XCD-chunked remap. Epilogue scatters q (x0.125) / k,v (t<381).
__global__ __launch_bounds__(256, 6) void gemm_qkv(const u16* __restrict__ A,
                                                   const u16* __restrict__ Bw,
                                                   const float* __restrict__ bias,
                                                   u16* __restrict__ q_buf,
                                                   u16* __restrict__ all_k,
                                                   u16* __restrict__ all_v) {
    const int K = 1024;
    __shared__ __align__(16) u16 Al[2][64 * 32];     // 4KB per buf
    __shared__ __align__(16) u16 Bl[2][128 * 32];    // 8KB per buf
    const int tid = threadIdx.x;
    const int wv = tid >> 6, lane = tid & 63;
    const int lg = lane >> 4, lr = lane & 15;
    const int id = blockIdx.x + blockIdx.y * gridDim.x;
    const int per = (gridDim.x * gridDim.y) >> 3;    // 1536/8 = 192
    const int nid = (id & 7) * per + (id >> 3);      // XCD-chunked remap
    const int m0 = (nid % gridDim.x) * 64;
    const int n0 = (nid / gridDim.x) * 128;
    f32x4 acc[4][2] = {};
    // staging geometry (both-sides swizzle, rule 21)
    const int sa = wv * 64 + lane;                   // A seg (256 total)
    const int ar = sa >> 2,  ac = ((sa & 3) << 4) ^ (((ar >> 1) & 3) << 4);
    const int b0r = sa >> 2, b0c = ac;               // B seg 0 (rows 0..63)
    const int sb1 = 256 + sa;
    const int b1r = sb1 >> 2, b1c = ((sb1 & 3) << 4) ^ (((b1r >> 1) & 3) << 4);
    const int dstw = wv * 1024;                      // wave-uniform LDS chunk

    auto stage = [&](int kt, int buf) {
        const size_t ko = (size_t)kt << 5;
        gload16((const char*)A  + (((size_t)(m0 + ar) * K + ko) << 1) + ac,
                (char*)&Al[buf][0] + dstw);
        gload16((const char*)Bw + (((size_t)(n0 + b0r) * K + ko) << 1) + b0c,
                (char*)&Bl[buf][0] + dstw);
        gload16((const char*)Bw + (((size_t)(n0 + b1r) * K + ko) << 1) + b1c,
                (char*)&Bl[buf][0] + 4096 + dstw);
    };
    stage(0, 0);
    __syncthreads();
    int cur = 0;
    for (int kt = 0; kt < 32; ++kt) {
        const char* At = (const char*)&Al[cur][0];
        const char* Bt = (const char*)&Bl[cur][0];
        bf16x8 af[4], bq[2];
        #pragma unroll
        for (int mi = 0; mi < 4; ++mi) {             // A rows 0..63
            int row = mi * 16 + lr;
            af[mi] = *(const bf16x8*)(At + row * 64 + ((lg << 4) ^ (((row >> 1) & 3) << 4)));
        }
        #pragma unroll
        for (int ni = 0; ni < 2; ++ni) {             // B rows wv*32 .. +32
            int row = wv * 32 + ni * 16 + lr;
            bq[ni] = *(const bf16x8*)(Bt + row * 64 + ((lg << 4) ^ (((row >> 1) & 3) << 4)));
        }
        if (kt + 1 < 32) stage(kt + 1, cur ^ 1);
        __builtin_amdgcn_s_setprio(1);
        #pragma unroll
        for (int mi = 0; mi < 4; ++mi)
            #pragma unroll
            for (int ni = 0; ni < 2; ++ni)
                acc[mi][ni] = __builtin_amdgcn_mfma_f32_16x16x32_bf16(af[mi], bq[ni], acc[mi][ni], 0, 0, 0);
        __builtin_amdgcn_s_setprio(0);
        __syncthreads();
        cur ^= 1;
    }
    #pragma unroll
    for (int mi = 0; mi < 4; ++mi)
        #pragma unroll
        for (int ni = 0; ni < 2; ++ni)
            #pragma unroll
            for (int r = 0; r < 4; ++r) {
                int mm = m0 + mi * 16 + lg * 4 + r;        // D row = (lane>>4)*4+reg
                int nn = n0 + wv * 32 + ni * 16 + lr;      // D col = lane&15
                float v = acc[mi][ni][r] + bias[nn];
                int which = nn >> 10, c = nn & 1023, h = c >> 6, d = c & 63;
                int b = mm >> 10, t = mm & 1023;
                int bh = b * 16 + h;
                if (which == 0) {
                    q_buf[((size_t)bh * 1024 + t) * 64 + d] = f2bf(v * 0.125f);
                } else if (t < 381) {                      // concat col 643+t <= 1023
                    u16* dst = (which == 1) ? all_k : all_v;
                    dst[((size_t)bh * 1024 + 643 + t) * 64 + d] = f2bf(v);
                }
            }
}

// ------------- GEMM: 128^2 tile, BK=32, 32KB dbuf LDS, swizzled ------------
// Template MODE/KSPLIT (compile-time). MODE 0: f32+bias. MODE 2: f32 partial
// at outF[ks*partStride + m*N + n].
template<int MODE, int KSPLIT>
__global__ __launch_bounds__(256) void gemm128(const u16* __restrict__ A,
                                               const u16* __restrict__ Bw,
                                               const float* __restrict__ bias,
                                               int K, int N,
                                               float* __restrict__ outF,
                                               size_t partStride) {
    __shared__ __align__(16) u16 Al[2][128 * 32];   // 8KB per buf
    __shared__ __align__(16) u16 Bl[2][128 * 32];
    const int tid = threadIdx.x;
    const int wv = tid >> 6, lane = tid & 63;
    const int lg = lane >> 4, lr = lane & 15;
    const int wr = (wv >> 1) * 64, wc = (wv & 1) * 64;
    const int id = blockIdx.x + blockIdx.y * gridDim.x;
    const int per = (gridDim.x * gridDim.y) >> 3;      // grids are %8==0
    const int nid = (id & 7) * per + (id >> 3);        // XCD-chunked remap
    const int m0 = (nid % gridDim.x) * 128;
    const int rest = nid / gridDim.x;
    const int nt = rest / KSPLIT, ks = rest % KSPLIT;
    const int n0 = nt * 128;
    const int Kp = K / KSPLIT;
    const int koff = ks * Kp;
    f32x4 acc[4][4] = {};
    const int sr0 = tid >> 2,         sc0 = ((tid & 3) << 4) ^ (((sr0 >> 1) & 3) << 4);
    const int sr1 = (tid + 256) >> 2, sc1 = ((tid & 3) << 4) ^ (((sr1 >> 1) & 3) << 4);
    const int dA0 = wv * 1024;
    const int dA1 = 4096 + wv * 1024;
    const int nk = Kp >> 5;
    gload16((const char*)A  + (((size_t)(m0 + sr0) * K + koff) << 1) + sc0, (char*)&Al[0][0] + dA0);
    gload16((const char*)A  + (((size_t)(m0 + sr1) * K + koff) << 1) + sc1, (char*)&Al[0][0] + dA1);
    gload16((const char*)Bw + (((size_t)(n0 + sr0) * K + koff) << 1) + sc0, (char*)&Bl[0][0] + dA0);
    gload16((const char*)Bw + (((size_t)(n0 + sr1) * K + koff) << 1) + sc1, (char*)&Bl[0][0] + dA1);
    __syncthreads();
    int cur = 0;
    for (int kt = 0; kt < nk; ++kt) {
        const char* At = (const char*)&Al[cur][0];
        const char* Bt = (const char*)&Bl[cur][0];
        bf16x8 af[4], bq[4];
        #pragma unroll
        for (int mi = 0; mi < 4; ++mi) {
            int row = wr + mi * 16 + lr;
            af[mi] = *(const bf16x8*)(At + row * 64 + ((lg << 4) ^ (((row >> 1) & 3) << 4)));
        }
        #pragma unroll
        for (int ni = 0; ni < 4; ++ni) {
            int row = wc + ni * 16 + lr;
            bq[ni] = *(const bf16x8*)(Bt + row * 64 + ((lg << 4) ^ (((row >> 1) & 3) << 4)));
        }
        if (kt + 1 < nk) {
            const size_t ko = koff + ((size_t)(kt + 1) << 5);
            char* Ad = (char*)&Al[cur ^ 1][0];
            char* Bd = (char*)&Bl[cur ^ 1][0];
            gload16((const char*)A  + (((size_t)(m0 + sr0) * K + ko) << 1) + sc0, Ad + dA0);
            gload16((const char*)A  + (((size_t)(m0 + sr1) * K + ko) << 1) + sc1, Ad + dA1);
            gload16((const char*)Bw + (((size_t)(n0 + sr0) * K + ko) << 1) + sc0, Bd + dA0);
            gload16((const char*)Bw + (((size_t)(n0 + sr1) * K + ko) << 1) + sc1, Bd + dA1);
        }
        __builtin_amdgcn_s_setprio(1);
        #pragma unroll
        for (int mi = 0; mi < 4; ++mi)
            #pragma unroll
            for (int ni = 0; ni < 4; ++ni)
                acc[mi][ni] = __builtin_amdgcn_mfma_f32_16x16x32_bf16(af[mi], bq[ni], acc[mi][ni], 0, 0, 0);
        __builtin_amdgcn_s_setprio(0);
        __syncthreads();
        cur ^= 1;
    }
    #pragma unroll
    for (int mi = 0; mi < 4; ++mi)
        #pragma unroll
        for (int ni = 0; ni < 4; ++ni)
            #pragma unroll
            for (int r = 0; r < 4; ++r) {
                int mm = m0 + wr + mi * 16 + lg * 4 + r;
                int nn = n0 + wc + ni * 16 + lr;
                if (MODE == 0) {
                    outF[(size_t)mm * N + nn] = acc[mi][ni][r] + bias[nn];
                } else {
                    outF[(size_t)ks * partStride + (size_t)mm * N + nn] = acc[mi][ni][r];
                }
            }
}

// ------------- combine: out = pp0 + pp1 + bias (proj split-K) --------------
__global__ __launch_bounds__(256) void combine_proj(const float* __restrict__ pp0,
                                                    const float* __restrict__ pp1,
                                                    const float* __restrict__ bias,
                                                    float* __restrict__ out) {
    int i = blockIdx.x * 256 + threadIdx.x;       // 1,048,576 float4 units
    float4 a = ((const float4*)pp0)[i];
    float4 b = ((const float4*)pp1)[i];
    float4 bs = ((const float4*)bias)[i & 255];
    float4 o;
    o.x = a.x + b.x + bs.x; o.y = a.y + b.y + bs.y;
    o.z = a.z + b.z + bs.z; o.w = a.w + b.w + bs.w;
    ((float4*)out)[i] = o;
}

// ------------------------------- attention ---------------------------------
__global__ __launch_bounds__(256) void attn_kernel(const u16* __restrict__ Q,
                                                   const u16* __restrict__ Kc,
                                                   const u16* __restrict__ VT,
                                                   u16* __restrict__ Y) {
    __shared__ __align__(16) u16 Kl[2][4096];
    __shared__ __align__(16) u16 Vl[2][4096];
    __shared__ __align__(16) u16 P_w[4][16 * 64];
    const int tid = threadIdx.x;
    const int lane = tid & 63;
    const int w = tid >> 6;
    const int lg = lane >> 4, lr = lane & 15;
    const int bh = blockIdx.x;
    const int pair = blockIdx.y;
    const u16* Kb = Kc + (size_t)bh * 65536;
    const u16* Vb = VT + (size_t)bh * 65536;
    char* Pbase = (char*)&P_w[w][0];
    const int xorq = (lr & 7) << 4;

    const int r0 = tid >> 3,         c0 = ((tid & 7) * 16) ^ ((r0 & 7) << 4);
    const int r1 = (tid + 256) >> 3, c1 = ((tid & 7) * 16) ^ ((r1 & 7) << 4);
    const int dst0 = w * 1024;

    for (int phase = 0; phase < 2; ++phase) {
        const int qt = phase ? (15 - pair) : pair;
        const int q0 = qt * 64;
        const u16* Qb = Q + ((size_t)bh * 1024 + q0 + w * 16) * 64;
        bf16x8 qf0 = *(const bf16x8*)&Qb[lr * 64 + lg * 8];
        bf16x8 qf1 = *(const bf16x8*)&Qb[lr * 64 + 32 + lg * 8];
        f32x4 o[4] = {};
        float m = -1e30f, lsum = 0.f;
        const int i_q = q0 + w * 16 + lr;

        {
            const char* Ks = (const char*)Kb;
            gload16(Ks + ((size_t)r0 << 7) + c0, (char*)&Kl[0][0] + dst0);
            gload16(Ks + ((size_t)r1 << 7) + c1, (char*)&Kl[0][0] + 4096 + dst0);
            gload16((const char*)Vb + ((size_t)r0 << 11) + c0, (char*)&Vl[0][0] + dst0);
            gload16((const char*)Vb + ((size_t)r1 << 11) + c1, (char*)&Vl[0][0] + 4096 + dst0);
        }
        __syncthreads();
        int cur = 0;

        for (int kt = 0; kt <= qt; ++kt) {
            if (kt < qt) {
                const int k0n = (kt + 1) * 64;
                const char* Ks = (const char*)Kb + ((size_t)k0n << 7);
                const char* Vs = (const char*)Vb + ((size_t)k0n << 1);
                char* Kd = (char*)&Kl[cur ^ 1][0];
                char* Vd = (char*)&Vl[cur ^ 1][0];
                gload16(Ks + ((size_t)r0 << 7) + c0, Kd + dst0);
                gload16(Ks + ((size_t)r1 << 7) + c1, Kd + 4096 + dst0);
                gload16(Vs + ((size_t)r0 << 11) + c0, Vd + dst0);
                gload16(Vs + ((size_t)r1 << 11) + c1, Vd + 4096 + dst0);
            }
            const char* Kt = (const char*)&Kl[cur][0];
            const char* Vt = (const char*)&Vl[cur][0];
            f32x4 st[4] = {};
            __builtin_amdgcn_s_setprio(1);
            #pragma unroll
            for (int hh = 0; hh < 4; ++hh) {
                const char* Kr = Kt + (size_t)(hh * 16 + lr) * 128;
                bf16x8 kf0 = *(const bf16x8*)(Kr + ((lg * 16) ^ xorq));
                bf16x8 kf1 = *(const bf16x8*)(Kr + ((64 + lg * 16) ^ xorq));
                st[hh] = __builtin_amdgcn_mfma_f32_16x16x32_bf16(kf0, qf0, st[hh], 0, 0, 0);
                st[hh] = __builtin_amdgcn_mfma_f32_16x16x32_bf16(kf1, qf1, st[hh], 0, 0, 0);
            }
            __builtin_amdgcn_s_setprio(0);
            const int k0 = kt * 64;
            float sv[16];
            float tmax = -1e30f;
            if (kt == qt) {
                #pragma unroll
                for (int hh = 0; hh < 4; ++hh)
                    #pragma unroll
                    for (int r = 0; r < 4; ++r) {
                        int j = k0 + hh * 16 + lg * 4 + r;
                        float s = (j <= i_q) ? st[hh][r] : -1e30f;
                        sv[hh * 4 + r] = s;
                        tmax = fmaxf(tmax, s);
                    }
            } else {
                #pragma unroll
                for (int hh = 0; hh < 4; ++hh)
                    #pragma unroll
                    for (int r = 0; r < 4; ++r) {
                        float s = st[hh][r];
                        sv[hh * 4 + r] = s;
                        tmax = fmaxf(tmax, s);
                    }
            }
            tmax = fmaxf(tmax, __shfl_xor(tmax, 16));
            tmax = fmaxf(tmax, __shfl_xor(tmax, 32));
            if (!__all(tmax - m <= 8.f)) {
                float mnew = fmaxf(m, tmax);
                float alpha = __expf(m - mnew);
                #pragma unroll
                for (int c = 0; c < 4; ++c) {
                    o[c][0] *= alpha; o[c][1] *= alpha; o[c][2] *= alpha; o[c][3] *= alpha;
                }
                lsum *= alpha;
                m = mnew;
            }
            float psum = 0.f;
            #pragma unroll
            for (int hh = 0; hh < 4; ++hh) {
                u16x4 pk;
                #pragma unroll
                for (int r = 0; r < 4; ++r) {
                    float p = __expf(sv[hh * 4 + r] - m);
                    psum += p;
                    pk[r] = f2bf(p);
                }
                *(u16x4*)(Pbase + lr * 128 + ((hh * 32 + lg * 8) ^ xorq)) = pk;
            }
            psum += __shfl_xor(psum, 16);
            psum += __shfl_xor(psum, 32);
            lsum += psum;
            asm volatile("s_waitcnt lgkmcnt(0)" ::: "memory");
            __builtin_amdgcn_sched_barrier(0);
            #pragma unroll
            for (int ks = 0; ks < 2; ++ks) {
                bf16x8 pf = *(const bf16x8*)(Pbase + lr * 128 + ((ks * 64 + lg * 16) ^ xorq));
                __builtin_amdgcn_s_setprio(1);
                #pragma unroll
                for (int c = 0; c < 4; ++c) {
                    const char* Vr = Vt + (size_t)(c * 16 + lr) * 128;
                    bf16x8 vf = *(const bf16x8*)(Vr + ((ks * 64 + lg * 16) ^ xorq));
                    o[c] = __builtin_amdgcn_mfma_f32_16x16x32_bf16(vf, pf, o[c], 0, 0, 0);
                }
                __builtin_amdgcn_s_setprio(0);
            }
            __syncthreads();
            cur ^= 1;
        }
        float inv = 1.0f / lsum;
        #pragma unroll
        for (int c = 0; c < 4; ++c) {
            u16x4 ov;
            #pragma unroll
            for (int r = 0; r < 4; ++r) ov[r] = f2bf(o[c][r] * inv);
            *(u16x4*)(Pbase + lr * 128 + (((c * 16 + lg * 4) * 2) ^ xorq)) = ov;
        }
        asm volatile("s_waitcnt lgkmcnt(0)" ::: "memory");
        __builtin_amdgcn_sched_barrier(0);
        const int b = bh >> 4, h = bh & 15;
        const int qr = lane >> 2, dseg = (lane & 3) * 16;
        const int xorr = (qr & 7) << 4;
        size_t g = ((size_t)(b * 1024 + q0 + w * 16 + qr)) * 1024 + h * 64 + dseg;
        *(u16x8*)&Y[g]     = *(const u16x8*)(Pbase + qr * 128 + ((dseg * 2) ^ xorr));
        *(u16x8*)&Y[g + 8] = *(const u16x8*)(Pbase + qr * 128 + ((dseg * 2 + 16) ^ xorr));
    }
}

// ---------------------------------------------------------------------------
extern "C" void kernel_launch(void* const* d_in, const int* in_sizes, int n_in,
                              void* d_out, int out_size, void* d_ws, size_t ws_size,
                              hipStream_t stream) {
    const float* x            = (const float*)d_in[0];
    const float* mem_k1       = (const float*)d_in[1];
    const float* mem_v1       = (const float*)d_in[2];
    const float* mem_k2       = (const float*)d_in[3];
    const float* mem_v2       = (const float*)d_in[4];
    const float* mem_k3       = (const float*)d_in[5];
    const float* mem_v3       = (const float*)d_in[6];
    const float* c_attn_w     = (const float*)d_in[7];
    const float* c_attn_b     = (const float*)d_in[8];
    const float* c_proj_w     = (const float*)d_in[9];
    const float* c_proj_b     = (const float*)d_in[10];
    const float* compress_k_w = (const float*)d_in[11];
    const float* ln_k_g       = (const float*)d_in[12];
    const float* ln_k_b       = (const float*)d_in[13];
    const float* compress_v_w = (const float*)d_in[14];
    const float* ln_v_g       = (const float*)d_in[15];
    const float* ln_v_b       = (const float*)d_in[16];

    char* ws = (char*)d_ws;
    u16* x_bf   = (u16*)(ws);                     // [4096][1024]   8 MB (dead after qkv)
    u16* all_vT = (u16*)(ws);                     // [64][64][1024] 8 MB (reuses x_bf)
    u16* wq_bf  = (u16*)(ws + (8u << 20));        // [3072][1024]   6 MB
    u16* wp_bf  = (u16*)(ws + (14u << 20));       // [1024][1024]   2 MB
    u16* q_buf  = (u16*)(ws + (16u << 20));       // [64][1024][64] 8 MB
    u16* all_k  = (u16*)(ws + (24u << 20));       // [64][1024][64] 8 MB
    u16* all_v  = (u16*)(ws + (32u << 20));       // [64][1024][64] 8 MB
    u16* att_y  = (u16*)(ws + (40u << 20));       // [4096][1024]   8 MB
    float* pp1  = (float*)(ws + (16u << 20));     // 16 MB (recycles q_buf+all_k post-attn)
    float* pp0  = (float*)(ws + (48u << 20));     // 16 MB (needs ws >= 64MB)
    float* out = (float*)d_out;

    cvt_all<<<8192, 256, 0, stream>>>(x, c_attn_w, c_proj_w, x_bf, wq_bf, wp_bf);

    prep_mem<<<dim3(322, 64), 256, 0, stream>>>(mem_k1, mem_v1, mem_k2, mem_v2,
                                                mem_k3, mem_v3,
                                                compress_k_w, ln_k_g, ln_k_b,
                                                compress_v_w, ln_v_g, ln_v_b,
                                                all_k, all_v);

    // qkv: M=4096, N=3072, K=1024 -> scatter q/k/v (64x128 tiles, 6 blocks/CU)
    gemm_qkv<<<dim3(64, 24), 256, 0, stream>>>(x_bf, wq_bf, c_attn_b,
                                               q_buf, all_k, all_v);

    transpose_v<<<dim3(16, 64), 256, 0, stream>>>(all_v, all_vT);

    // attention: x = bh (XCD locality), y = q-tile pair (load balance)
    attn_kernel<<<dim3(64, 8), 256, 0, stream>>>(q_buf, all_k, all_vT, att_y);

    if (ws_size >= (64ull << 20)) {
        // proj split-K=2 (template): 512 blocks, partials pp0/pp1, then combine.
        size_t stride = (size_t)(pp1 - pp0);
        gemm128<2, 2><<<dim3(32, 16), 256, 0, stream>>>(att_y, wp_bf, nullptr, 1024, 1024,
                                                        pp0, stride);
        combine_proj<<<4096, 256, 0, stream>>>(pp0, pp0 + stride, c_proj_b, out);
    } else {
        gemm128<0, 1><<<dim3(32, 8), 256, 0, stream>>>(att_y, wp_bf, c_proj_b, 1024, 1024,
                                                       out, 0);
    }
}

// Round 16
// 129.541 us; speedup vs baseline: 1.0008x; 1.0008x over previous
//
#include <hip/hip_runtime.h>

// ---------------------------------------------------------------------------
// MemoryCausalSelfAttention for MI355X (gfx950).
// Model (R4-R11): per-CU staging rate = ~3.4 B/cyc x resident blocks/CU.
// qkv GEMM: 64x128 tile, 24KB LDS -> 6 blocks/CU (grid 1536) for 2x rate.
// proj GEMM: split-K=2 (template) + f32 combine pass (validated ~24us R11).
// Fused prep/cvt; flash attention (XCD-local, balanced pairs, LDS K/V).
// Causal mask over concat axis => only first 1024 keys ever attended.
// ---------------------------------------------------------------------------

using u16    = unsigned short;
using bf16x8 = __attribute__((ext_vector_type(8))) __bf16;
using f32x4  = __attribute__((ext_vector_type(4))) float;
using u16x8  = __attribute__((ext_vector_type(8))) unsigned short;
using u16x4  = __attribute__((ext_vector_type(4))) unsigned short;

__device__ __forceinline__ u16 f2bf(float f) {
    union { float f; unsigned u; } v; v.f = f;
    unsigned r = v.u + 0x7FFFu + ((v.u >> 16) & 1u);   // RNE
    return (u16)(r >> 16);
}

__device__ __forceinline__ void gload16(const void* src, const void* lds_base) {
    __builtin_amdgcn_global_load_lds(
        (const __attribute__((address_space(1))) void*)src,
        (__attribute__((address_space(3))) void*)lds_base, 16, 0, 0);
}

// ------------------- fused f32->bf16 conversions (x, Wqkv, Wproj) ----------
__global__ __launch_bounds__(256) void cvt_all(const float* __restrict__ x,
                                               const float* __restrict__ wa,
                                               const float* __restrict__ wp,
                                               u16* __restrict__ xb,
                                               u16* __restrict__ wab,
                                               u16* __restrict__ wpb) {
    int i = blockIdx.x * 256 + threadIdx.x;      // 2,097,152 float4 units total
    const float4* s; u16x4* d; int j;
    if (i < 1048576)      { s = (const float4*)x;  d = (u16x4*)xb;  j = i; }
    else if (i < 1835008) { s = (const float4*)wa; d = (u16x4*)wab; j = i - 1048576; }
    else                  { s = (const float4*)wp; d = (u16x4*)wpb; j = i - 1835008; }
    float4 f = s[j];
    u16x4 o; o[0] = f2bf(f.x); o[1] = f2bf(f.y); o[2] = f2bf(f.z); o[3] = f2bf(f.w);
    d[j] = o;
}

// ---- fused mem prep: copy k1/v1/k2/v2 + conv(k=2,s=2,p=1)+LN for k3/v3 ----
__global__ __launch_bounds__(256) void prep_mem(const float* __restrict__ k1,
                                                const float* __restrict__ v1,
                                                const float* __restrict__ k2,
                                                const float* __restrict__ v2,
                                                const float* __restrict__ k3,
                                                const float* __restrict__ v3,
                                                const float* __restrict__ wk,
                                                const float* __restrict__ gk,
                                                const float* __restrict__ bk,
                                                const float* __restrict__ wv,
                                                const float* __restrict__ gv,
                                                const float* __restrict__ bv,
                                                u16* __restrict__ all_k,
                                                u16* __restrict__ all_v) {
    const int bh = blockIdx.y;
    const int ru = blockIdx.x * 4 + (threadIdx.x >> 6);
    const int d = threadIdx.x & 63;
    if (ru >= 1286) return;
    if (ru < 772) {                                   // plain copies
        const float* src; u16* dst; int t, ro, L;
        if (ru < 129)      { t = ru;       src = k1; dst = all_k; ro = 0;   L = 129; }
        else if (ru < 258) { t = ru - 129; src = v1; dst = all_v; ro = 0;   L = 129; }
        else if (ru < 515) { t = ru - 258; src = k2; dst = all_k; ro = 129; L = 257; }
        else               { t = ru - 515; src = v2; dst = all_v; ro = 129; L = 257; }
        float v = src[((size_t)bh * L + t) * 64 + d];
        dst[((size_t)bh * 1024 + ro + t) * 64 + d] = f2bf(v);
    } else {                                          // compress + LN (ro=386)
        const float* seg; const float* w; const float* g; const float* bta; u16* dst; int t;
        if (ru < 1029) { t = ru - 772;  seg = k3; w = wk; g = gk; bta = bk; dst = all_k; }
        else           { t = ru - 1029; seg = v3; w = wv; g = gv; bta = bv; dst = all_v; }
        const float* sb = seg + (size_t)bh * 513 * 64;
        float x0 = (t > 0) ? sb[(size_t)(2 * t - 1) * 64 + d] : 0.f;
        float x1 = sb[(size_t)(2 * t) * 64 + d];
        float y = w[2 * d] * x0 + w[2 * d + 1] * x1;
        float s = y;
        #pragma unroll
        for (int o = 32; o; o >>= 1) s += __shfl_xor(s, o);
        float mu = s * (1.f / 64.f);
        float dv = y - mu;
        float s2 = dv * dv;
        #pragma unroll
        for (int o = 32; o; o >>= 1) s2 += __shfl_xor(s2, o);
        float var = s2 * (1.f / 64.f);
        float out = dv * rsqrtf(var + 1e-5f) * g[d] + bta[d];
        dst[((size_t)bh * 1024 + 386 + t) * 64 + d] = f2bf(out);
    }
}

// ----------------- V transpose: [bh][1024][64] -> [bh][64][1024] -----------
__global__ __launch_bounds__(256) void transpose_v(const u16* __restrict__ src,
                                                   u16* __restrict__ dst) {
    __shared__ u16 tile[64][66];
    const int bh = blockIdx.y, t0 = blockIdx.x * 64;
    const int tid = threadIdx.x;
    #pragma unroll
    for (int i = 0; i < 2; ++i) {
        int p = tid + i * 256;
        int tr = p >> 3, dc = (p & 7) * 8;
        *(u16x8*)&tile[tr][dc] = *(const u16x8*)&src[((size_t)bh * 1024 + t0 + tr) * 64 + dc];
    }
    __syncthreads();
    #pragma unroll
    for (int i = 0; i < 2; ++i) {
        int p = tid + i * 256;
        int d = p >> 3, tc = (p & 7) * 8;
        u16x8 v;
        #pragma unroll
        for (int e = 0; e < 8; ++e) v[e] = tile[tc + e][d];
        *(u16x8*)&dst[((size_t)bh * 64 + d) * 1024 + t0 + tc] = v;
    }
}

// --------- qkv GEMM: 64x128 tile, BK=32, 24KB dbuf LDS, 6 blocks/CU --------
// A [M][K]=x_bf, W [N][K]=wq. 4 waves side-by-side in n (each 64 rows x 32
// cols, acc[4][2]). Per iter: frag reads -> stage(t+1) (A 1 + B 2 gload16
// per thread) -> 8 MFMA -> barrier. Swizzle X(row)=((row>>1)&3)<<4 applied
// both-sides. XCD-chunked remap. Epilogue scatters q (x0.125) / k,v (t<381).
__global__ __launch_bounds__(256, 6) void gemm_qkv(const u16* __restrict__ A,
                                                   const u16* __restrict__ Bw,
                                                   const float* __restrict__ bias,
                                                   u16* __restrict__ q_buf,
                                                   u16* __restrict__ all_k,
                                                   u16* __restrict__ all_v) {
    const int K = 1024;
    __shared__ __align__(16) u16 Al[2][64 * 32];     // 4KB per buf
    __shared__ __align__(16) u16 Bl[2][128 * 32];    // 8KB per buf
    const int tid = threadIdx.x;
    const int wv = tid >> 6, lane = tid & 63;
    const int lg = lane >> 4, lr = lane & 15;
    const int id = blockIdx.x + blockIdx.y * gridDim.x;
    const int per = (gridDim.x * gridDim.y) >> 3;    // 1536/8 = 192
    const int nid = (id & 7) * per + (id >> 3);      // XCD-chunked remap
    const int m0 = (nid % gridDim.x) * 64;
    const int n0 = (nid / gridDim.x) * 128;
    f32x4 acc[4][2] = {};
    // staging geometry (both-sides swizzle, rule 21)
    const int sa = wv * 64 + lane;                   // A seg (256 total)
    const int ar = sa >> 2,  ac = ((sa & 3) << 4) ^ (((ar >> 1) & 3) << 4);
    const int b0r = sa >> 2, b0c = ac;               // B seg 0 (rows 0..63)
    const int sb1 = 256 + sa;
    const int b1r = sb1 >> 2, b1c = ((sb1 & 3) << 4) ^ (((b1r >> 1) & 3) << 4);
    const int dstw = wv * 1024;                      // wave-uniform LDS chunk

    auto stage = [&](int kt, int buf) {
        const size_t ko = (size_t)kt << 5;
        gload16((const char*)A  + (((size_t)(m0 + ar) * K + ko) << 1) + ac,
                (char*)&Al[buf][0] + dstw);
        gload16((const char*)Bw + (((size_t)(n0 + b0r) * K + ko) << 1) + b0c,
                (char*)&Bl[buf][0] + dstw);
        gload16((const char*)Bw + (((size_t)(n0 + b1r) * K + ko) << 1) + b1c,
                (char*)&Bl[buf][0] + 4096 + dstw);
    };
    stage(0, 0);
    __syncthreads();
    int cur = 0;
    for (int kt = 0; kt < 32; ++kt) {
        const char* At = (const char*)&Al[cur][0];
        const char* Bt = (const char*)&Bl[cur][0];
        bf16x8 af[4], bq[2];
        #pragma unroll
        for (int mi = 0; mi < 4; ++mi) {             // A rows 0..63
            int row = mi * 16 + lr;
            af[mi] = *(const bf16x8*)(At + row * 64 + ((lg << 4) ^ (((row >> 1) & 3) << 4)));
        }
        #pragma unroll
        for (int ni = 0; ni < 2; ++ni) {             // B rows wv*32 .. +32
            int row = wv * 32 + ni * 16 + lr;
            bq[ni] = *(const bf16x8*)(Bt + row * 64 + ((lg << 4) ^ (((row >> 1) & 3) << 4)));
        }
        if (kt + 1 < 32) stage(kt + 1, cur ^ 1);
        __builtin_amdgcn_s_setprio(1);
        #pragma unroll
        for (int mi = 0; mi < 4; ++mi)
            #pragma unroll
            for (int ni = 0; ni < 2; ++ni)
                acc[mi][ni] = __builtin_amdgcn_mfma_f32_16x16x32_bf16(af[mi], bq[ni], acc[mi][ni], 0, 0, 0);
        __builtin_amdgcn_s_setprio(0);
        __syncthreads();
        cur ^= 1;
    }
    #pragma unroll
    for (int mi = 0; mi < 4; ++mi)
        #pragma unroll
        for (int ni = 0; ni < 2; ++ni)
            #pragma unroll
            for (int r = 0; r < 4; ++r) {
                int mm = m0 + mi * 16 + lg * 4 + r;        // D row = (lane>>4)*4+reg
                int nn = n0 + wv * 32 + ni * 16 + lr;      // D col = lane&15
                float v = acc[mi][ni][r] + bias[nn];
                int which = nn >> 10, c = nn & 1023, h = c >> 6, d = c & 63;
                int b = mm >> 10, t = mm & 1023;
                int bh = b * 16 + h;
                if (which == 0) {
                    q_buf[((size_t)bh * 1024 + t) * 64 + d] = f2bf(v * 0.125f);
                } else if (t < 381) {                      // concat col 643+t <= 1023
                    u16* dst = (which == 1) ? all_k : all_v;
                    dst[((size_t)bh * 1024 + 643 + t) * 64 + d] = f2bf(v);
                }
            }
}

// ------------- GEMM: 128^2 tile, BK=32, 32KB dbuf LDS, swizzled ------------
// Template MODE/KSPLIT (compile-time). MODE 0: f32+bias. MODE 2: f32 partial
// at outF[ks*partStride + m*N + n].
template<int MODE, int KSPLIT>
__global__ __launch_bounds__(256) void gemm128(const u16* __restrict__ A,
                                               const u16* __restrict__ Bw,
                                               const float* __restrict__ bias,
                                               int K, int N,
                                               float* __restrict__ outF,
                                               size_t partStride) {
    __shared__ __align__(16) u16 Al[2][128 * 32];   // 8KB per buf
    __shared__ __align__(16) u16 Bl[2][128 * 32];
    const int tid = threadIdx.x;
    const int wv = tid >> 6, lane = tid & 63;
    const int lg = lane >> 4, lr = lane & 15;
    const int wr = (wv >> 1) * 64, wc = (wv & 1) * 64;
    const int id = blockIdx.x + blockIdx.y * gridDim.x;
    const int per = (gridDim.x * gridDim.y) >> 3;      // grids are %8==0
    const int nid = (id & 7) * per + (id >> 3);        // XCD-chunked remap
    const int m0 = (nid % gridDim.x) * 128;
    const int rest = nid / gridDim.x;
    const int nt = rest / KSPLIT, ks = rest % KSPLIT;
    const int n0 = nt * 128;
    const int Kp = K / KSPLIT;
    const int koff = ks * Kp;
    f32x4 acc[4][4] = {};
    const int sr0 = tid >> 2,         sc0 = ((tid & 3) << 4) ^ (((sr0 >> 1) & 3) << 4);
    const int sr1 = (tid + 256) >> 2, sc1 = ((tid & 3) << 4) ^ (((sr1 >> 1) & 3) << 4);
    const int dA0 = wv * 1024;
    const int dA1 = 4096 + wv * 1024;
    const int nk = Kp >> 5;
    gload16((const char*)A  + (((size_t)(m0 + sr0) * K + koff) << 1) + sc0, (char*)&Al[0][0] + dA0);
    gload16((const char*)A  + (((size_t)(m0 + sr1) * K + koff) << 1) + sc1, (char*)&Al[0][0] + dA1);
    gload16((const char*)Bw + (((size_t)(n0 + sr0) * K + koff) << 1) + sc0, (char*)&Bl[0][0] + dA0);
    gload16((const char*)Bw + (((size_t)(n0 + sr1) * K + koff) << 1) + sc1, (char*)&Bl[0][0] + dA1);
    __syncthreads();
    int cur = 0;
    for (int kt = 0; kt < nk; ++kt) {
        const char* At = (const char*)&Al[cur][0];
        const char* Bt = (const char*)&Bl[cur][0];
        bf16x8 af[4], bq[4];
        #pragma unroll
        for (int mi = 0; mi < 4; ++mi) {
            int row = wr + mi * 16 + lr;
            af[mi] = *(const bf16x8*)(At + row * 64 + ((lg << 4) ^ (((row >> 1) & 3) << 4)));
        }
        #pragma unroll
        for (int ni = 0; ni < 4; ++ni) {
            int row = wc + ni * 16 + lr;
            bq[ni] = *(const bf16x8*)(Bt + row * 64 + ((lg << 4) ^ (((row >> 1) & 3) << 4)));
        }
        if (kt + 1 < nk) {
            const size_t ko = koff + ((size_t)(kt + 1) << 5);
            char* Ad = (char*)&Al[cur ^ 1][0];
            char* Bd = (char*)&Bl[cur ^ 1][0];
            gload16((const char*)A  + (((size_t)(m0 + sr0) * K + ko) << 1) + sc0, Ad + dA0);
            gload16((const char*)A  + (((size_t)(m0 + sr1) * K + ko) << 1) + sc1, Ad + dA1);
            gload16((const char*)Bw + (((size_t)(n0 + sr0) * K + ko) << 1) + sc0, Bd + dA0);
            gload16((const char*)Bw + (((size_t)(n0 + sr1) * K + ko) << 1) + sc1, Bd + dA1);
        }
        __builtin_amdgcn_s_setprio(1);
        #pragma unroll
        for (int mi = 0; mi < 4; ++mi)
            #pragma unroll
            for (int ni = 0; ni < 4; ++ni)
                acc[mi][ni] = __builtin_amdgcn_mfma_f32_16x16x32_bf16(af[mi], bq[ni], acc[mi][ni], 0, 0, 0);
        __builtin_amdgcn_s_setprio(0);
        __syncthreads();
        cur ^= 1;
    }
    #pragma unroll
    for (int mi = 0; mi < 4; ++mi)
        #pragma unroll
        for (int ni = 0; ni < 4; ++ni)
            #pragma unroll
            for (int r = 0; r < 4; ++r) {
                int mm = m0 + wr + mi * 16 + lg * 4 + r;
                int nn = n0 + wc + ni * 16 + lr;
                if (MODE == 0) {
                    outF[(size_t)mm * N + nn] = acc[mi][ni][r] + bias[nn];
                } else {
                    outF[(size_t)ks * partStride + (size_t)mm * N + nn] = acc[mi][ni][r];
                }
            }
}

// ------------- combine: out = pp0 + pp1 + bias (proj split-K) --------------
__global__ __launch_bounds__(256) void combine_proj(const float* __restrict__ pp0,
                                                    const float* __restrict__ pp1,
                                                    const float* __restrict__ bias,
                                                    float* __restrict__ out) {
    int i = blockIdx.x * 256 + threadIdx.x;       // 1,048,576 float4 units
    float4 a = ((const float4*)pp0)[i];
    float4 b = ((const float4*)pp1)[i];
    float4 bs = ((const float4*)bias)[i & 255];
    float4 o;
    o.x = a.x + b.x + bs.x; o.y = a.y + b.y + bs.y;
    o.z = a.z + b.z + bs.z; o.w = a.w + b.w + bs.w;
    ((float4*)out)[i] = o;
}

// ------------------------------- attention ---------------------------------
__global__ __launch_bounds__(256) void attn_kernel(const u16* __restrict__ Q,
                                                   const u16* __restrict__ Kc,
                                                   const u16* __restrict__ VT,
                                                   u16* __restrict__ Y) {
    __shared__ __align__(16) u16 Kl[2][4096];
    __shared__ __align__(16) u16 Vl[2][4096];
    __shared__ __align__(16) u16 P_w[4][16 * 64];
    const int tid = threadIdx.x;
    const int lane = tid & 63;
    const int w = tid >> 6;
    const int lg = lane >> 4, lr = lane & 15;
    const int bh = blockIdx.x;
    const int pair = blockIdx.y;
    const u16* Kb = Kc + (size_t)bh * 65536;
    const u16* Vb = VT + (size_t)bh * 65536;
    char* Pbase = (char*)&P_w[w][0];
    const int xorq = (lr & 7) << 4;

    const int r0 = tid >> 3,         c0 = ((tid & 7) * 16) ^ ((r0 & 7) << 4);
    const int r1 = (tid + 256) >> 3, c1 = ((tid & 7) * 16) ^ ((r1 & 7) << 4);
    const int dst0 = w * 1024;

    for (int phase = 0; phase < 2; ++phase) {
        const int qt = phase ? (15 - pair) : pair;
        const int q0 = qt * 64;
        const u16* Qb = Q + ((size_t)bh * 1024 + q0 + w * 16) * 64;
        bf16x8 qf0 = *(const bf16x8*)&Qb[lr * 64 + lg * 8];
        bf16x8 qf1 = *(const bf16x8*)&Qb[lr * 64 + 32 + lg * 8];
        f32x4 o[4] = {};
        float m = -1e30f, lsum = 0.f;
        const int i_q = q0 + w * 16 + lr;

        {
            const char* Ks = (const char*)Kb;
            gload16(Ks + ((size_t)r0 << 7) + c0, (char*)&Kl[0][0] + dst0);
            gload16(Ks + ((size_t)r1 << 7) + c1, (char*)&Kl[0][0] + 4096 + dst0);
            gload16((const char*)Vb + ((size_t)r0 << 11) + c0, (char*)&Vl[0][0] + dst0);
            gload16((const char*)Vb + ((size_t)r1 << 11) + c1, (char*)&Vl[0][0] + 4096 + dst0);
        }
        __syncthreads();
        int cur = 0;

        for (int kt = 0; kt <= qt; ++kt) {
            if (kt < qt) {
                const int k0n = (kt + 1) * 64;
                const char* Ks = (const char*)Kb + ((size_t)k0n << 7);
                const char* Vs = (const char*)Vb + ((size_t)k0n << 1);
                char* Kd = (char*)&Kl[cur ^ 1][0];
                char* Vd = (char*)&Vl[cur ^ 1][0];
                gload16(Ks + ((size_t)r0 << 7) + c0, Kd + dst0);
                gload16(Ks + ((size_t)r1 << 7) + c1, Kd + 4096 + dst0);
                gload16(Vs + ((size_t)r0 << 11) + c0, Vd + dst0);
                gload16(Vs + ((size_t)r1 << 11) + c1, Vd + 4096 + dst0);
            }
            const char* Kt = (const char*)&Kl[cur][0];
            const char* Vt = (const char*)&Vl[cur][0];
            f32x4 st[4] = {};
            __builtin_amdgcn_s_setprio(1);
            #pragma unroll
            for (int hh = 0; hh < 4; ++hh) {
                const char* Kr = Kt + (size_t)(hh * 16 + lr) * 128;
                bf16x8 kf0 = *(const bf16x8*)(Kr + ((lg * 16) ^ xorq));
                bf16x8 kf1 = *(const bf16x8*)(Kr + ((64 + lg * 16) ^ xorq));
                st[hh] = __builtin_amdgcn_mfma_f32_16x16x32_bf16(kf0, qf0, st[hh], 0, 0, 0);
                st[hh] = __builtin_amdgcn_mfma_f32_16x16x32_bf16(kf1, qf1, st[hh], 0, 0, 0);
            }
            __builtin_amdgcn_s_setprio(0);
            const int k0 = kt * 64;
            float sv[16];
            float tmax = -1e30f;
            if (kt == qt) {
                #pragma unroll
                for (int hh = 0; hh < 4; ++hh)
                    #pragma unroll
                    for (int r = 0; r < 4; ++r) {
                        int j = k0 + hh * 16 + lg * 4 + r;
                        float s = (j <= i_q) ? st[hh][r] : -1e30f;
                        sv[hh * 4 + r] = s;
                        tmax = fmaxf(tmax, s);
                    }
            } else {
                #pragma unroll
                for (int hh = 0; hh < 4; ++hh)
                    #pragma unroll
                    for (int r = 0; r < 4; ++r) {
                        float s = st[hh][r];
                        sv[hh * 4 + r] = s;
                        tmax = fmaxf(tmax, s);
                    }
            }
            tmax = fmaxf(tmax, __shfl_xor(tmax, 16));
            tmax = fmaxf(tmax, __shfl_xor(tmax, 32));
            if (!__all(tmax - m <= 8.f)) {
                float mnew = fmaxf(m, tmax);
                float alpha = __expf(m - mnew);
                #pragma unroll
                for (int c = 0; c < 4; ++c) {
                    o[c][0] *= alpha; o[c][1] *= alpha; o[c][2] *= alpha; o[c][3] *= alpha;
                }
                lsum *= alpha;
                m = mnew;
            }
            float psum = 0.f;
            #pragma unroll
            for (int hh = 0; hh < 4; ++hh) {
                u16x4 pk;
                #pragma unroll
                for (int r = 0; r < 4; ++r) {
                    float p = __expf(sv[hh * 4 + r] - m);
                    psum += p;
                    pk[r] = f2bf(p);
                }
                *(u16x4*)(Pbase + lr * 128 + ((hh * 32 + lg * 8) ^ xorq)) = pk;
            }
            psum += __shfl_xor(psum, 16);
            psum += __shfl_xor(psum, 32);
            lsum += psum;
            asm volatile("s_waitcnt lgkmcnt(0)" ::: "memory");
            __builtin_amdgcn_sched_barrier(0);
            #pragma unroll
            for (int ks = 0; ks < 2; ++ks) {
                bf16x8 pf = *(const bf16x8*)(Pbase + lr * 128 + ((ks * 64 + lg * 16) ^ xorq));
                __builtin_amdgcn_s_setprio(1);
                #pragma unroll
                for (int c = 0; c < 4; ++c) {
                    const char* Vr = Vt + (size_t)(c * 16 + lr) * 128;
                    bf16x8 vf = *(const bf16x8*)(Vr + ((ks * 64 + lg * 16) ^ xorq));
                    o[c] = __builtin_amdgcn_mfma_f32_16x16x32_bf16(vf, pf, o[c], 0, 0, 0);
                }
                __builtin_amdgcn_s_setprio(0);
            }
            __syncthreads();
            cur ^= 1;
        }
        float inv = 1.0f / lsum;
        #pragma unroll
        for (int c = 0; c < 4; ++c) {
            u16x4 ov;
            #pragma unroll
            for (int r = 0; r < 4; ++r) ov[r] = f2bf(o[c][r] * inv);
            *(u16x4*)(Pbase + lr * 128 + (((c * 16 + lg * 4) * 2) ^ xorq)) = ov;
        }
        asm volatile("s_waitcnt lgkmcnt(0)" ::: "memory");
        __builtin_amdgcn_sched_barrier(0);
        const int b = bh >> 4, h = bh & 15;
        const int qr = lane >> 2, dseg = (lane & 3) * 16;
        const int xorr = (qr & 7) << 4;
        size_t g = ((size_t)(b * 1024 + q0 + w * 16 + qr)) * 1024 + h * 64 + dseg;
        *(u16x8*)&Y[g]     = *(const u16x8*)(Pbase + qr * 128 + ((dseg * 2) ^ xorr));
        *(u16x8*)&Y[g + 8] = *(const u16x8*)(Pbase + qr * 128 + ((dseg * 2 + 16) ^ xorr));
    }
}

// ---------------------------------------------------------------------------
extern "C" void kernel_launch(void* const* d_in, const int* in_sizes, int n_in,
                              void* d_out, int out_size, void* d_ws, size_t ws_size,
                              hipStream_t stream) {
    const float* x            = (const float*)d_in[0];
    const float* mem_k1       = (const float*)d_in[1];
    const float* mem_v1       = (const float*)d_in[2];
    const float* mem_k2       = (const float*)d_in[3];
    const float* mem_v2       = (const float*)d_in[4];
    const float* mem_k3       = (const float*)d_in[5];
    const float* mem_v3       = (const float*)d_in[6];
    const float* c_attn_w     = (const float*)d_in[7];
    const float* c_attn_b     = (const float*)d_in[8];
    const float* c_proj_w     = (const float*)d_in[9];
    const float* c_proj_b     = (const float*)d_in[10];
    const float* compress_k_w = (const float*)d_in[11];
    const float* ln_k_g       = (const float*)d_in[12];
    const float* ln_k_b       = (const float*)d_in[13];
    const float* compress_v_w = (const float*)d_in[14];
    const float* ln_v_g       = (const float*)d_in[15];
    const float* ln_v_b       = (const float*)d_in[16];

    char* ws = (char*)d_ws;
    u16* x_bf   = (u16*)(ws);                     // [4096][1024]   8 MB (dead after qkv)
    u16* all_vT = (u16*)(ws);                     // [64][64][1024] 8 MB (reuses x_bf)
    u16* wq_bf  = (u16*)(ws + (8u << 20));        // [3072][1024]   6 MB
    u16* wp_bf  = (u16*)(ws + (14u << 20));       // [1024][1024]   2 MB
    u16* q_buf  = (u16*)(ws + (16u << 20));       // [64][1024][64] 8 MB
    u16* all_k  = (u16*)(ws + (24u << 20));       // [64][1024][64] 8 MB
    u16* all_v  = (u16*)(ws + (32u << 20));       // [64][1024][64] 8 MB
    u16* att_y  = (u16*)(ws + (40u << 20));       // [4096][1024]   8 MB
    float* pp1  = (float*)(ws + (16u << 20));     // 16 MB (recycles q_buf+all_k post-attn)
    float* pp0  = (float*)(ws + (48u << 20));     // 16 MB (needs ws >= 64MB)
    float* out = (float*)d_out;

    cvt_all<<<8192, 256, 0, stream>>>(x, c_attn_w, c_proj_w, x_bf, wq_bf, wp_bf);

    prep_mem<<<dim3(322, 64), 256, 0, stream>>>(mem_k1, mem_v1, mem_k2, mem_v2,
                                                mem_k3, mem_v3,
                                                compress_k_w, ln_k_g, ln_k_b,
                                                compress_v_w, ln_v_g, ln_v_b,
                                                all_k, all_v);

    // qkv: M=4096, N=3072, K=1024 -> scatter q/k/v (64x128 tiles, 6 blocks/CU)
    gemm_qkv<<<dim3(64, 24), 256, 0, stream>>>(x_bf, wq_bf, c_attn_b,
                                               q_buf, all_k, all_v);

    transpose_v<<<dim3(16, 64), 256, 0, stream>>>(all_v, all_vT);

    // attention: x = bh (XCD locality), y = q-tile pair (load balance)
    attn_kernel<<<dim3(64, 8), 256, 0, stream>>>(q_buf, all_k, all_vT, att_y);

    if (ws_size >= (64ull << 20)) {
        // proj split-K=2 (template): 512 blocks, partials pp0/pp1, then combine.
        size_t stride = (size_t)(pp1 - pp0);
        gemm128<2, 2><<<dim3(32, 16), 256, 0, stream>>>(att_y, wp_bf, nullptr, 1024, 1024,
                                                        pp0, stride);
        combine_proj<<<4096, 256, 0, stream>>>(pp0, pp0 + stride, c_proj_b, out);
    } else {
        gemm128<0, 1><<<dim3(32, 8), 256, 0, stream>>>(att_y, wp_bf, c_proj_b, 1024, 1024,
                                                       out, 0);
    }
}

// Round 17
// 126.777 us; speedup vs baseline: 1.0227x; 1.0218x over previous
//
#include <hip/hip_runtime.h>

// ---------------------------------------------------------------------------
// MemoryCausalSelfAttention for MI355X (gfx950).
// Model (R4-R16): per-block staging time = (loads/thread) x per-load latency;
// per-load latency is the L2-MISS round trip (~1200cyc) when the XCD's A/B
// slice exceeds the 4MB L2. Fix: 2D XCD patches sized to fit L2.
//   qkv: 4m x 2n patches (A 2MB + B 3MB), proj: 8m x 1n (A 1MB + B 2MB).
// qkv GEMM: 64x128 tile, 6 blocks/CU. proj: split-K=2 + f32 combine.
// Causal mask over concat axis => only first 1024 keys ever attended.
// ---------------------------------------------------------------------------

using u16    = unsigned short;
using bf16x8 = __attribute__((ext_vector_type(8))) __bf16;
using f32x4  = __attribute__((ext_vector_type(4))) float;
using u16x8  = __attribute__((ext_vector_type(8))) unsigned short;
using u16x4  = __attribute__((ext_vector_type(4))) unsigned short;

__device__ __forceinline__ u16 f2bf(float f) {
    union { float f; unsigned u; } v; v.f = f;
    unsigned r = v.u + 0x7FFFu + ((v.u >> 16) & 1u);   // RNE
    return (u16)(r >> 16);
}

__device__ __forceinline__ void gload16(const void* src, const void* lds_base) {
    __builtin_amdgcn_global_load_lds(
        (const __attribute__((address_space(1))) void*)src,
        (__attribute__((address_space(3))) void*)lds_base, 16, 0, 0);
}

// ------------------- fused f32->bf16 conversions (x, Wqkv, Wproj) ----------
__global__ __launch_bounds__(256) void cvt_all(const float* __restrict__ x,
                                               const float* __restrict__ wa,
                                               const float* __restrict__ wp,
                                               u16* __restrict__ xb,
                                               u16* __restrict__ wab,
                                               u16* __restrict__ wpb) {
    int i = blockIdx.x * 256 + threadIdx.x;      // 2,097,152 float4 units total
    const float4* s; u16x4* d; int j;
    if (i < 1048576)      { s = (const float4*)x;  d = (u16x4*)xb;  j = i; }
    else if (i < 1835008) { s = (const float4*)wa; d = (u16x4*)wab; j = i - 1048576; }
    else                  { s = (const float4*)wp; d = (u16x4*)wpb; j = i - 1835008; }
    float4 f = s[j];
    u16x4 o; o[0] = f2bf(f.x); o[1] = f2bf(f.y); o[2] = f2bf(f.z); o[3] = f2bf(f.w);
    d[j] = o;
}

// ---- fused mem prep: copy k1/v1/k2/v2 + conv(k=2,s=2,p=1)+LN for k3/v3 ----
__global__ __launch_bounds__(256) void prep_mem(const float* __restrict__ k1,
                                                const float* __restrict__ v1,
                                                const float* __restrict__ k2,
                                                const float* __restrict__ v2,
                                                const float* __restrict__ k3,
                                                const float* __restrict__ v3,
                                                const float* __restrict__ wk,
                                                const float* __restrict__ gk,
                                                const float* __restrict__ bk,
                                                const float* __restrict__ wv,
                                                const float* __restrict__ gv,
                                                const float* __restrict__ bv,
                                                u16* __restrict__ all_k,
                                                u16* __restrict__ all_v) {
    const int bh = blockIdx.y;
    const int ru = blockIdx.x * 4 + (threadIdx.x >> 6);
    const int d = threadIdx.x & 63;
    if (ru >= 1286) return;
    if (ru < 772) {                                   // plain copies
        const float* src; u16* dst; int t, ro, L;
        if (ru < 129)      { t = ru;       src = k1; dst = all_k; ro = 0;   L = 129; }
        else if (ru < 258) { t = ru - 129; src = v1; dst = all_v; ro = 0;   L = 129; }
        else if (ru < 515) { t = ru - 258; src = k2; dst = all_k; ro = 129; L = 257; }
        else               { t = ru - 515; src = v2; dst = all_v; ro = 129; L = 257; }
        float v = src[((size_t)bh * L + t) * 64 + d];
        dst[((size_t)bh * 1024 + ro + t) * 64 + d] = f2bf(v);
    } else {                                          // compress + LN (ro=386)
        const float* seg; const float* w; const float* g; const float* bta; u16* dst; int t;
        if (ru < 1029) { t = ru - 772;  seg = k3; w = wk; g = gk; bta = bk; dst = all_k; }
        else           { t = ru - 1029; seg = v3; w = wv; g = gv; bta = bv; dst = all_v; }
        const float* sb = seg + (size_t)bh * 513 * 64;
        float x0 = (t > 0) ? sb[(size_t)(2 * t - 1) * 64 + d] : 0.f;
        float x1 = sb[(size_t)(2 * t) * 64 + d];
        float y = w[2 * d] * x0 + w[2 * d + 1] * x1;
        float s = y;
        #pragma unroll
        for (int o = 32; o; o >>= 1) s += __shfl_xor(s, o);
        float mu = s * (1.f / 64.f);
        float dv = y - mu;
        float s2 = dv * dv;
        #pragma unroll
        for (int o = 32; o; o >>= 1) s2 += __shfl_xor(s2, o);
        float var = s2 * (1.f / 64.f);
        float out = dv * rsqrtf(var + 1e-5f) * g[d] + bta[d];
        dst[((size_t)bh * 1024 + 386 + t) * 64 + d] = f2bf(out);
    }
}

// ----------------- V transpose: [bh][1024][64] -> [bh][64][1024] -----------
__global__ __launch_bounds__(256) void transpose_v(const u16* __restrict__ src,
                                                   u16* __restrict__ dst) {
    __shared__ u16 tile[64][66];
    const int bh = blockIdx.y, t0 = blockIdx.x * 64;
    const int tid = threadIdx.x;
    #pragma unroll
    for (int i = 0; i < 2; ++i) {
        int p = tid + i * 256;
        int tr = p >> 3, dc = (p & 7) * 8;
        *(u16x8*)&tile[tr][dc] = *(const u16x8*)&src[((size_t)bh * 1024 + t0 + tr) * 64 + dc];
    }
    __syncthreads();
    #pragma unroll
    for (int i = 0; i < 2; ++i) {
        int p = tid + i * 256;
        int d = p >> 3, tc = (p & 7) * 8;
        u16x8 v;
        #pragma unroll
        for (int e = 0; e < 8; ++e) v[e] = tile[tc + e][d];
        *(u16x8*)&dst[((size_t)bh * 64 + d) * 1024 + t0 + tc] = v;
    }
}

// --------- qkv GEMM: 64x128 tile, BK=32, 24KB dbuf LDS, 6 blocks/CU --------
// XCD remap: 4m x 2n patches -> per-XCD footprint A 2MB + B 3MB (~L2-fit).
// 4 waves side-by-side in n (each 64x32, acc[4][2]). Per iter: frag reads ->
// stage(t+1) (3 gload16/thread) -> 8 MFMA -> barrier. Both-sides swizzle.
__global__ __launch_bounds__(256, 6) void gemm_qkv(const u16* __restrict__ A,
                                                   const u16* __restrict__ Bw,
                                                   const float* __restrict__ bias,
                                                   u16* __restrict__ q_buf,
                                                   u16* __restrict__ all_k,
                                                   u16* __restrict__ all_v) {
    const int K = 1024;
    __shared__ __align__(16) u16 Al[2][64 * 32];     // 4KB per buf
    __shared__ __align__(16) u16 Bl[2][128 * 32];    // 8KB per buf
    const int tid = threadIdx.x;
    const int wv = tid >> 6, lane = tid & 63;
    const int lg = lane >> 4, lr = lane & 15;
    // 2D XCD patches: grid (64 m-tiles, 24 n-tiles); 4m x 2n XCD grid.
    // Per XCD: 16 m-tiles (1024 rows, 2MB A) x 12 n-tiles (1536 cols, 3MB B).
    const int id = blockIdx.x + blockIdx.y * gridDim.x;
    const int xcd = id & 7, lid = id >> 3;           // lid in [0,192)
    const int pm = xcd >> 1, pn = xcd & 1;
    const int lm = lid & 15, ln = lid >> 4;          // 16 x 12 within patch
    const int m0 = (pm * 16 + lm) * 64;
    const int n0 = (pn * 12 + ln) * 128;
    f32x4 acc[4][2] = {};
    // staging geometry (both-sides swizzle, rule 21)
    const int sa = wv * 64 + lane;                   // A seg (256 total)
    const int ar = sa >> 2,  ac = ((sa & 3) << 4) ^ (((ar >> 1) & 3) << 4);
    const int b0r = sa >> 2, b0c = ac;               // B seg 0 (rows 0..63)
    const int sb1 = 256 + sa;
    const int b1r = sb1 >> 2, b1c = ((sb1 & 3) << 4) ^ (((b1r >> 1) & 3) << 4);
    const int dstw = wv * 1024;                      // wave-uniform LDS chunk

    auto stage = [&](int kt, int buf) {
        const size_t ko = (size_t)kt << 5;
        gload16((const char*)A  + (((size_t)(m0 + ar) * K + ko) << 1) + ac,
                (char*)&Al[buf][0] + dstw);
        gload16((const char*)Bw + (((size_t)(n0 + b0r) * K + ko) << 1) + b0c,
                (char*)&Bl[buf][0] + dstw);
        gload16((const char*)Bw + (((size_t)(n0 + b1r) * K + ko) << 1) + b1c,
                (char*)&Bl[buf][0] + 4096 + dstw);
    };
    stage(0, 0);
    __syncthreads();
    int cur = 0;
    for (int kt = 0; kt < 32; ++kt) {
        const char* At = (const char*)&Al[cur][0];
        const char* Bt = (const char*)&Bl[cur][0];
        bf16x8 af[4], bq[2];
        #pragma unroll
        for (int mi = 0; mi < 4; ++mi) {             // A rows 0..63
            int row = mi * 16 + lr;
            af[mi] = *(const bf16x8*)(At + row * 64 + ((lg << 4) ^ (((row >> 1) & 3) << 4)));
        }
        #pragma unroll
        for (int ni = 0; ni < 2; ++ni) {             // B rows wv*32 .. +32
            int row = wv * 32 + ni * 16 + lr;
            bq[ni] = *(const bf16x8*)(Bt + row * 64 + ((lg << 4) ^ (((row >> 1) & 3) << 4)));
        }
        if (kt + 1 < 32) stage(kt + 1, cur ^ 1);
        __builtin_amdgcn_s_setprio(1);
        #pragma unroll
        for (int mi = 0; mi < 4; ++mi)
            #pragma unroll
            for (int ni = 0; ni < 2; ++ni)
                acc[mi][ni] = __builtin_amdgcn_mfma_f32_16x16x32_bf16(af[mi], bq[ni], acc[mi][ni], 0, 0, 0);
        __builtin_amdgcn_s_setprio(0);
        __syncthreads();
        cur ^= 1;
    }
    #pragma unroll
    for (int mi = 0; mi < 4; ++mi)
        #pragma unroll
        for (int ni = 0; ni < 2; ++ni)
            #pragma unroll
            for (int r = 0; r < 4; ++r) {
                int mm = m0 + mi * 16 + lg * 4 + r;        // D row = (lane>>4)*4+reg
                int nn = n0 + wv * 32 + ni * 16 + lr;      // D col = lane&15
                float v = acc[mi][ni][r] + bias[nn];
                int which = nn >> 10, c = nn & 1023, h = c >> 6, d = c & 63;
                int b = mm >> 10, t = mm & 1023;
                int bh = b * 16 + h;
                if (which == 0) {
                    q_buf[((size_t)bh * 1024 + t) * 64 + d] = f2bf(v * 0.125f);
                } else if (t < 381) {                      // concat col 643+t <= 1023
                    u16* dst = (which == 1) ? all_k : all_v;
                    dst[((size_t)bh * 1024 + 643 + t) * 64 + d] = f2bf(v);
                }
            }
}

// ------------- GEMM: 128^2 tile, BK=32, 32KB dbuf LDS, swizzled ------------
// Template MODE/KSPLIT. XCD remap: 8m x 1n patches -> per-XCD A 1MB + B 2MB
// (fully L2-resident for proj). MODE 0: f32+bias. MODE 2: f32 partial at
// outF[ks*partStride + m*N + n].
template<int MODE, int KSPLIT>
__global__ __launch_bounds__(256) void gemm128(const u16* __restrict__ A,
                                               const u16* __restrict__ Bw,
                                               const float* __restrict__ bias,
                                               int K, int N,
                                               float* __restrict__ outF,
                                               size_t partStride) {
    __shared__ __align__(16) u16 Al[2][128 * 32];   // 8KB per buf
    __shared__ __align__(16) u16 Bl[2][128 * 32];
    const int tid = threadIdx.x;
    const int wv = tid >> 6, lane = tid & 63;
    const int lg = lane >> 4, lr = lane & 15;
    const int wr = (wv >> 1) * 64, wc = (wv & 1) * 64;
    // 2D XCD patches: 8m x 1n. mpx = gridDim.x/8 m-tiles per XCD; all
    // (n,k)-combos (gridDim.y) within each XCD.
    const int id = blockIdx.x + blockIdx.y * gridDim.x;
    const int xcd = id & 7, lid = id >> 3;
    const int mpx = gridDim.x >> 3;
    const int lm = lid % mpx, ly = lid / mpx;
    const int m0 = (xcd * mpx + lm) * 128;
    const int nt = ly / KSPLIT, ks = ly % KSPLIT;
    const int n0 = nt * 128;
    const int Kp = K / KSPLIT;
    const int koff = ks * Kp;
    f32x4 acc[4][4] = {};
    const int sr0 = tid >> 2,         sc0 = ((tid & 3) << 4) ^ (((sr0 >> 1) & 3) << 4);
    const int sr1 = (tid + 256) >> 2, sc1 = ((tid & 3) << 4) ^ (((sr1 >> 1) & 3) << 4);
    const int dA0 = wv * 1024;
    const int dA1 = 4096 + wv * 1024;
    const int nk = Kp >> 5;
    gload16((const char*)A  + (((size_t)(m0 + sr0) * K + koff) << 1) + sc0, (char*)&Al[0][0] + dA0);
    gload16((const char*)A  + (((size_t)(m0 + sr1) * K + koff) << 1) + sc1, (char*)&Al[0][0] + dA1);
    gload16((const char*)Bw + (((size_t)(n0 + sr0) * K + koff) << 1) + sc0, (char*)&Bl[0][0] + dA0);
    gload16((const char*)Bw + (((size_t)(n0 + sr1) * K + koff) << 1) + sc1, (char*)&Bl[0][0] + dA1);
    __syncthreads();
    int cur = 0;
    for (int kt = 0; kt < nk; ++kt) {
        const char* At = (const char*)&Al[cur][0];
        const char* Bt = (const char*)&Bl[cur][0];
        bf16x8 af[4], bq[4];
        #pragma unroll
        for (int mi = 0; mi < 4; ++mi) {
            int row = wr + mi * 16 + lr;
            af[mi] = *(const bf16x8*)(At + row * 64 + ((lg << 4) ^ (((row >> 1) & 3) << 4)));
        }
        #pragma unroll
        for (int ni = 0; ni < 4; ++ni) {
            int row = wc + ni * 16 + lr;
            bq[ni] = *(const bf16x8*)(Bt + row * 64 + ((lg << 4) ^ (((row >> 1) & 3) << 4)));
        }
        if (kt + 1 < nk) {
            const size_t ko = koff + ((size_t)(kt + 1) << 5);
            char* Ad = (char*)&Al[cur ^ 1][0];
            char* Bd = (char*)&Bl[cur ^ 1][0];
            gload16((const char*)A  + (((size_t)(m0 + sr0) * K + ko) << 1) + sc0, Ad + dA0);
            gload16((const char*)A  + (((size_t)(m0 + sr1) * K + ko) << 1) + sc1, Ad + dA1);
            gload16((const char*)Bw + (((size_t)(n0 + sr0) * K + ko) << 1) + sc0, Bd + dA0);
            gload16((const char*)Bw + (((size_t)(n0 + sr1) * K + ko) << 1) + sc1, Bd + dA1);
        }
        __builtin_amdgcn_s_setprio(1);
        #pragma unroll
        for (int mi = 0; mi < 4; ++mi)
            #pragma unroll
            for (int ni = 0; ni < 4; ++ni)
                acc[mi][ni] = __builtin_amdgcn_mfma_f32_16x16x32_bf16(af[mi], bq[ni], acc[mi][ni], 0, 0, 0);
        __builtin_amdgcn_s_setprio(0);
        __syncthreads();
        cur ^= 1;
    }
    #pragma unroll
    for (int mi = 0; mi < 4; ++mi)
        #pragma unroll
        for (int ni = 0; ni < 4; ++ni)
            #pragma unroll
            for (int r = 0; r < 4; ++r) {
                int mm = m0 + wr + mi * 16 + lg * 4 + r;
                int nn = n0 + wc + ni * 16 + lr;
                if (MODE == 0) {
                    outF[(size_t)mm * N + nn] = acc[mi][ni][r] + bias[nn];
                } else {
                    outF[(size_t)ks * partStride + (size_t)mm * N + nn] = acc[mi][ni][r];
                }
            }
}

// ------------- combine: out = pp0 + pp1 + bias (proj split-K) --------------
__global__ __launch_bounds__(256) void combine_proj(const float* __restrict__ pp0,
                                                    const float* __restrict__ pp1,
                                                    const float* __restrict__ bias,
                                                    float* __restrict__ out) {
    int i = blockIdx.x * 256 + threadIdx.x;       // 1,048,576 float4 units
    float4 a = ((const float4*)pp0)[i];
    float4 b = ((const float4*)pp1)[i];
    float4 bs = ((const float4*)bias)[i & 255];
    float4 o;
    o.x = a.x + b.x + bs.x; o.y = a.y + b.y + bs.y;
    o.z = a.z + b.z + bs.z; o.w = a.w + b.w + bs.w;
    ((float4*)out)[i] = o;
}

// ------------------------------- attention ---------------------------------
__global__ __launch_bounds__(256) void attn_kernel(const u16* __restrict__ Q,
                                                   const u16* __restrict__ Kc,
                                                   const u16* __restrict__ VT,
                                                   u16* __restrict__ Y) {
    __shared__ __align__(16) u16 Kl[2][4096];
    __shared__ __align__(16) u16 Vl[2][4096];
    __shared__ __align__(16) u16 P_w[4][16 * 64];
    const int tid = threadIdx.x;
    const int lane = tid & 63;
    const int w = tid >> 6;
    const int lg = lane >> 4, lr = lane & 15;
    const int bh = blockIdx.x;
    const int pair = blockIdx.y;
    const u16* Kb = Kc + (size_t)bh * 65536;
    const u16* Vb = VT + (size_t)bh * 65536;
    char* Pbase = (char*)&P_w[w][0];
    const int xorq = (lr & 7) << 4;

    const int r0 = tid >> 3,         c0 = ((tid & 7) * 16) ^ ((r0 & 7) << 4);
    const int r1 = (tid + 256) >> 3, c1 = ((tid & 7) * 16) ^ ((r1 & 7) << 4);
    const int dst0 = w * 1024;

    for (int phase = 0; phase < 2; ++phase) {
        const int qt = phase ? (15 - pair) : pair;
        const int q0 = qt * 64;
        const u16* Qb = Q + ((size_t)bh * 1024 + q0 + w * 16) * 64;
        bf16x8 qf0 = *(const bf16x8*)&Qb[lr * 64 + lg * 8];
        bf16x8 qf1 = *(const bf16x8*)&Qb[lr * 64 + 32 + lg * 8];
        f32x4 o[4] = {};
        float m = -1e30f, lsum = 0.f;
        const int i_q = q0 + w * 16 + lr;

        {
            const char* Ks = (const char*)Kb;
            gload16(Ks + ((size_t)r0 << 7) + c0, (char*)&Kl[0][0] + dst0);
            gload16(Ks + ((size_t)r1 << 7) + c1, (char*)&Kl[0][0] + 4096 + dst0);
            gload16((const char*)Vb + ((size_t)r0 << 11) + c0, (char*)&Vl[0][0] + dst0);
            gload16((const char*)Vb + ((size_t)r1 << 11) + c1, (char*)&Vl[0][0] + 4096 + dst0);
        }
        __syncthreads();
        int cur = 0;

        for (int kt = 0; kt <= qt; ++kt) {
            if (kt < qt) {
                const int k0n = (kt + 1) * 64;
                const char* Ks = (const char*)Kb + ((size_t)k0n << 7);
                const char* Vs = (const char*)Vb + ((size_t)k0n << 1);
                char* Kd = (char*)&Kl[cur ^ 1][0];
                char* Vd = (char*)&Vl[cur ^ 1][0];
                gload16(Ks + ((size_t)r0 << 7) + c0, Kd + dst0);
                gload16(Ks + ((size_t)r1 << 7) + c1, Kd + 4096 + dst0);
                gload16(Vs + ((size_t)r0 << 11) + c0, Vd + dst0);
                gload16(Vs + ((size_t)r1 << 11) + c1, Vd + 4096 + dst0);
            }
            const char* Kt = (const char*)&Kl[cur][0];
            const char* Vt = (const char*)&Vl[cur][0];
            f32x4 st[4] = {};
            __builtin_amdgcn_s_setprio(1);
            #pragma unroll
            for (int hh = 0; hh < 4; ++hh) {
                const char* Kr = Kt + (size_t)(hh * 16 + lr) * 128;
                bf16x8 kf0 = *(const bf16x8*)(Kr + ((lg * 16) ^ xorq));
                bf16x8 kf1 = *(const bf16x8*)(Kr + ((64 + lg * 16) ^ xorq));
                st[hh] = __builtin_amdgcn_mfma_f32_16x16x32_bf16(kf0, qf0, st[hh], 0, 0, 0);
                st[hh] = __builtin_amdgcn_mfma_f32_16x16x32_bf16(kf1, qf1, st[hh], 0, 0, 0);
            }
            __builtin_amdgcn_s_setprio(0);
            const int k0 = kt * 64;
            float sv[16];
            float tmax = -1e30f;
            if (kt == qt) {
                #pragma unroll
                for (int hh = 0; hh < 4; ++hh)
                    #pragma unroll
                    for (int r = 0; r < 4; ++r) {
                        int j = k0 + hh * 16 + lg * 4 + r;
                        float s = (j <= i_q) ? st[hh][r] : -1e30f;
                        sv[hh * 4 + r] = s;
                        tmax = fmaxf(tmax, s);
                    }
            } else {
                #pragma unroll
                for (int hh = 0; hh < 4; ++hh)
                    #pragma unroll
                    for (int r = 0; r < 4; ++r) {
                        float s = st[hh][r];
                        sv[hh * 4 + r] = s;
                        tmax = fmaxf(tmax, s);
                    }
            }
            tmax = fmaxf(tmax, __shfl_xor(tmax, 16));
            tmax = fmaxf(tmax, __shfl_xor(tmax, 32));
            if (!__all(tmax - m <= 8.f)) {
                float mnew = fmaxf(m, tmax);
                float alpha = __expf(m - mnew);
                #pragma unroll
                for (int c = 0; c < 4; ++c) {
                    o[c][0] *= alpha; o[c][1] *= alpha; o[c][2] *= alpha; o[c][3] *= alpha;
                }
                lsum *= alpha;
                m = mnew;
            }
            float psum = 0.f;
            #pragma unroll
            for (int hh = 0; hh < 4; ++hh) {
                u16x4 pk;
                #pragma unroll
                for (int r = 0; r < 4; ++r) {
                    float p = __expf(sv[hh * 4 + r] - m);
                    psum += p;
                    pk[r] = f2bf(p);
                }
                *(u16x4*)(Pbase + lr * 128 + ((hh * 32 + lg * 8) ^ xorq)) = pk;
            }
            psum += __shfl_xor(psum, 16);
            psum += __shfl_xor(psum, 32);
            lsum += psum;
            asm volatile("s_waitcnt lgkmcnt(0)" ::: "memory");
            __builtin_amdgcn_sched_barrier(0);
            #pragma unroll
            for (int ks = 0; ks < 2; ++ks) {
                bf16x8 pf = *(const bf16x8*)(Pbase + lr * 128 + ((ks * 64 + lg * 16) ^ xorq));
                __builtin_amdgcn_s_setprio(1);
                #pragma unroll
                for (int c = 0; c < 4; ++c) {
                    const char* Vr = Vt + (size_t)(c * 16 + lr) * 128;
                    bf16x8 vf = *(const bf16x8*)(Vr + ((ks * 64 + lg * 16) ^ xorq));
                    o[c] = __builtin_amdgcn_mfma_f32_16x16x32_bf16(vf, pf, o[c], 0, 0, 0);
                }
                __builtin_amdgcn_s_setprio(0);
            }
            __syncthreads();
            cur ^= 1;
        }
        float inv = 1.0f / lsum;
        #pragma unroll
        for (int c = 0; c < 4; ++c) {
            u16x4 ov;
            #pragma unroll
            for (int r = 0; r < 4; ++r) ov[r] = f2bf(o[c][r] * inv);
            *(u16x4*)(Pbase + lr * 128 + (((c * 16 + lg * 4) * 2) ^ xorq)) = ov;
        }
        asm volatile("s_waitcnt lgkmcnt(0)" ::: "memory");
        __builtin_amdgcn_sched_barrier(0);
        const int b = bh >> 4, h = bh & 15;
        const int qr = lane >> 2, dseg = (lane & 3) * 16;
        const int xorr = (qr & 7) << 4;
        size_t g = ((size_t)(b * 1024 + q0 + w * 16 + qr)) * 1024 + h * 64 + dseg;
        *(u16x8*)&Y[g]     = *(const u16x8*)(Pbase + qr * 128 + ((dseg * 2) ^ xorr));
        *(u16x8*)&Y[g + 8] = *(const u16x8*)(Pbase + qr * 128 + ((dseg * 2 + 16) ^ xorr));
    }
}

// ---------------------------------------------------------------------------
extern "C" void kernel_launch(void* const* d_in, const int* in_sizes, int n_in,
                              void* d_out, int out_size, void* d_ws, size_t ws_size,
                              hipStream_t stream) {
    const float* x            = (const float*)d_in[0];
    const float* mem_k1       = (const float*)d_in[1];
    const float* mem_v1       = (const float*)d_in[2];
    const float* mem_k2       = (const float*)d_in[3];
    const float* mem_v2       = (const float*)d_in[4];
    const float* mem_k3       = (const float*)d_in[5];
    const float* mem_v3       = (const float*)d_in[6];
    const float* c_attn_w     = (const float*)d_in[7];
    const float* c_attn_b     = (const float*)d_in[8];
    const float* c_proj_w     = (const float*)d_in[9];
    const float* c_proj_b     = (const float*)d_in[10];
    const float* compress_k_w = (const float*)d_in[11];
    const float* ln_k_g       = (const float*)d_in[12];
    const float* ln_k_b       = (const float*)d_in[13];
    const float* compress_v_w = (const float*)d_in[14];
    const float* ln_v_g       = (const float*)d_in[15];
    const float* ln_v_b       = (const float*)d_in[16];

    char* ws = (char*)d_ws;
    u16* x_bf   = (u16*)(ws);                     // [4096][1024]   8 MB (dead after qkv)
    u16* all_vT = (u16*)(ws);                     // [64][64][1024] 8 MB (reuses x_bf)
    u16* wq_bf  = (u16*)(ws + (8u << 20));        // [3072][1024]   6 MB
    u16* wp_bf  = (u16*)(ws + (14u << 20));       // [1024][1024]   2 MB
    u16* q_buf  = (u16*)(ws + (16u << 20));       // [64][1024][64] 8 MB
    u16* all_k  = (u16*)(ws + (24u << 20));       // [64][1024][64] 8 MB
    u16* all_v  = (u16*)(ws + (32u << 20));       // [64][1024][64] 8 MB
    u16* att_y  = (u16*)(ws + (40u << 20));       // [4096][1024]   8 MB
    float* pp1  = (float*)(ws + (16u << 20));     // 16 MB (recycles q_buf+all_k post-attn)
    float* pp0  = (float*)(ws + (48u << 20));     // 16 MB (needs ws >= 64MB)
    float* out = (float*)d_out;

    cvt_all<<<8192, 256, 0, stream>>>(x, c_attn_w, c_proj_w, x_bf, wq_bf, wp_bf);

    prep_mem<<<dim3(322, 64), 256, 0, stream>>>(mem_k1, mem_v1, mem_k2, mem_v2,
                                                mem_k3, mem_v3,
                                                compress_k_w, ln_k_g, ln_k_b,
                                                compress_v_w, ln_v_g, ln_v_b,
                                                all_k, all_v);

    // qkv: M=4096, N=3072, K=1024 -> scatter q/k/v (64x128 tiles, 6 blocks/CU,
    // 4m x 2n XCD patches)
    gemm_qkv<<<dim3(64, 24), 256, 0, stream>>>(x_bf, wq_bf, c_attn_b,
                                               q_buf, all_k, all_v);

    transpose_v<<<dim3(16, 64), 256, 0, stream>>>(all_v, all_vT);

    // attention: x = bh (XCD locality), y = q-tile pair (load balance)
    attn_kernel<<<dim3(64, 8), 256, 0, stream>>>(q_buf, all_k, all_vT, att_y);

    if (ws_size >= (64ull << 20)) {
        // proj split-K=2: 512 blocks, 8m x 1n XCD patches (A 1MB + B 2MB, L2-fit)
        size_t stride = (size_t)(pp1 - pp0);
        gemm128<2, 2><<<dim3(32, 16), 256, 0, stream>>>(att_y, wp_bf, nullptr, 1024, 1024,
                                                        pp0, stride);
        combine_proj<<<4096, 256, 0, stream>>>(pp0, pp0 + stride, c_proj_b, out);
    } else {
        gemm128<0, 1><<<dim3(32, 8), 256, 0, stream>>>(att_y, wp_bf, c_proj_b, 1024, 1024,
                                                       out, 0);
    }
}